// Round 3
// baseline (800.011 us; speedup 1.0000x reference)
//
#include <hip/hip_runtime.h>
#include <hip/hip_bf16.h>

#define NN 384
#define DP 128
#define NHEAD 4
#define CH 32
#define HCC 128

typedef __hip_bfloat16 bf16;
typedef __bf16 bf16x8 __attribute__((ext_vector_type(8)));
typedef __bf16 bf16x4 __attribute__((ext_vector_type(4)));
typedef float floatx4 __attribute__((ext_vector_type(4)));

#define WSTRIDE 136   // weight/G-strip stride in bf16 elems (conflict-free b128)

__device__ __forceinline__ float b2f(bf16 x){ return __bfloat162float(x); }
__device__ __forceinline__ bf16 f2b(float x){ return __float2bfloat16(x); }

// Prep: Wt[col][d] = bf16(Wqkv[d][col]); col in [0,384), d in [0,128)
__global__ __launch_bounds__(256) void wt_kernel(
    const float* __restrict__ Wqkv, __bf16* __restrict__ Wt)
{
  int idx = blockIdx.x * 256 + threadIdx.x;   // 49152 total
  int d = idx / NN, col = idx - d * NN;
  Wt[col * DP + d] = (__bf16)Wqkv[idx];
}

// Prep: WgT[h][d] = Wg[d][h]; WoT[d][e] = Wo[e][d]  (both 128x128)
__global__ __launch_bounds__(256) void wgo_kernel(
    const float* __restrict__ Wg, const float* __restrict__ Wo,
    __bf16* __restrict__ WgT, __bf16* __restrict__ WoT)
{
  int idx = blockIdx.x * 256 + threadIdx.x;   // 16384 total
  int r = idx >> 7, c = idx & 127;
  WgT[idx] = (__bf16)Wg[c * 128 + r];
  WoT[idx] = (__bf16)Wo[c * 128 + r];
}

// Kernel A: LayerNorm + triangle bias. 32-lane group per position, float4 lanes.
__global__ __launch_bounds__(256) void ln_bias_kernel(
    const float* __restrict__ Zr, const float* __restrict__ lnw,
    const float* __restrict__ lnb, const float* __restrict__ Wb,
    bf16* __restrict__ Zn, float* __restrict__ bias)
{
  int t = threadIdx.x;
  int grp = t >> 5, lane32 = t & 31;
  int pos = blockIdx.x * 8 + grp;
  size_t base = (size_t)pos * DP;
  const float4 x = *(const float4*)(Zr + base + lane32 * 4);
  float s  = x.x + x.y + x.z + x.w;
  float s2 = x.x*x.x + x.y*x.y + x.z*x.z + x.w*x.w;
  #pragma unroll
  for (int m = 1; m < 32; m <<= 1){ s += __shfl_xor(s, m); s2 += __shfl_xor(s2, m); }
  float mean = s * (1.0f / DP);
  float var  = s2 * (1.0f / DP) - mean * mean;
  float rstd = rsqrtf(var + 1e-5f);
  const float4 w4 = *(const float4*)(lnw + lane32 * 4);
  const float4 b4 = *(const float4*)(lnb + lane32 * 4);
  float z0 = (x.x - mean) * rstd * w4.x + b4.x;
  float z1 = (x.y - mean) * rstd * w4.y + b4.y;
  float z2 = (x.z - mean) * rstd * w4.z + b4.z;
  float z3 = (x.w - mean) * rstd * w4.w + b4.w;
  bf16x4 zb = { (__bf16)z0, (__bf16)z1, (__bf16)z2, (__bf16)z3 };
  *(bf16x4*)((__bf16*)Zn + base + lane32 * 4) = zb;
  // bias partials: p[h] = sum_j z_j * Wb[(lane32*4+j)][h]
  const float4 wb0 = *(const float4*)(Wb + (lane32 * 4 + 0) * NHEAD);
  const float4 wb1 = *(const float4*)(Wb + (lane32 * 4 + 1) * NHEAD);
  const float4 wb2 = *(const float4*)(Wb + (lane32 * 4 + 2) * NHEAD);
  const float4 wb3 = *(const float4*)(Wb + (lane32 * 4 + 3) * NHEAD);
  float p0 = z0*wb0.x + z1*wb1.x + z2*wb2.x + z3*wb3.x;
  float p1 = z0*wb0.y + z1*wb1.y + z2*wb2.y + z3*wb3.y;
  float p2 = z0*wb0.z + z1*wb1.z + z2*wb2.z + z3*wb3.z;
  float p3 = z0*wb0.w + z1*wb1.w + z2*wb2.w + z3*wb3.w;
  #pragma unroll
  for (int m = 1; m < 32; m <<= 1){
    p0 += __shfl_xor(p0, m); p1 += __shfl_xor(p1, m);
    p2 += __shfl_xor(p2, m); p3 += __shfl_xor(p3, m);
  }
  if (lane32 == 0){
    bias[0 * NN * NN + pos] = p0;
    bias[1 * NN * NN + pos] = p1;
    bias[2 * NN * NN + pos] = p2;
    bias[3 * NN * NN + pos] = p3;
  }
}

// Kernel B: per (i, head): MFMA qkv projection + MFMA flash attention.
// R0 schedule, but P never touches LDS:
//  - QK^T computed SWAPPED (mfma(kf, qf)) so each lane's S row is q = m16.
//  - K-tile rows loaded PERMUTED: A-row m sources K-row 8*(m>>2)+(m&3)+4*tb,
//    so lane (m16,quad) ends up holding P[q=m16][k=32*kc+8*quad+j] — exactly
//    the PV A-fragment, built per-lane (no LDS, no cross-lane ops).
//  - bias/mask loads become float4 (4 consecutive k per reg).
//  - P normalized in-lane (q=m16) before pack -> no inv redistribution.
// LDS = qs 24K + ks 24K + vs 24K + maskb 1.5K = 75.3 KB -> 2 blocks/CU.
__global__ __launch_bounds__(256, 2) void attn_kernel(
    const __bf16* __restrict__ Zn, const __bf16* __restrict__ Wt,
    const float* __restrict__ Zm, const float* __restrict__ bias,
    __bf16* __restrict__ wa)
{
  __shared__ __align__(128) __bf16 qs[NN * 32];   // q: [row][c] swizzled
  __shared__ __align__(128) __bf16 ks[NN * 32];   // k: [row][c] swizzled
  __shared__ __align__(128) __bf16 vs[CH * NN];   // v^T: [c][row] swizzled
  __shared__ __align__(16) float maskb[NN];

  // XCD-aware bijective swizzle: 1536 blocks = 8 XCDs x 192.
  // All 4 heads of i and ~48 consecutive i's share one XCD's L2.
  int bid = blockIdx.x;
  int b = (bid & 7) * 192 + (bid >> 3);
  int i = b >> 2;
  int h = b & 3;
  int t = threadIdx.x;
  int wv = t >> 6;
  int lane = t & 63;
  int m16 = lane & 15;       // low-16 lane id
  int quad = lane >> 4;      // 0..3

  for (int k = t; k < NN; k += 256)
    maskb[k] = (Zm[(size_t)i * NN + k] - 1.0f) * 1e9f;

  const float qscale = 0.17677669529663687f; // 1/sqrt(32)

  // ---- Phase 1: qkv projection via MFMA (identical to R0, swizzled stores) ----
  for (int mt = wv * 6; mt < wv * 6 + 6; mt++){
    bf16x8 afr[4];
    const __bf16* arow = Zn + (size_t)(i * NN + mt * 16 + m16) * DP + quad * 8;
    #pragma unroll
    for (int kc = 0; kc < 4; kc++) afr[kc] = *(const bf16x8*)(arow + kc * 32);
    #pragma unroll
    for (int nt = 0; nt < 6; nt++){
      int mat = nt >> 1;
      int colbase = mat * HCC + h * CH + (nt & 1) * 16;
      const __bf16* brow = Wt + (size_t)(colbase + m16) * DP + quad * 8;
      floatx4 acc = {0.f, 0.f, 0.f, 0.f};
      #pragma unroll
      for (int kc = 0; kc < 4; kc++){
        bf16x8 bfr = *(const bf16x8*)(brow + kc * 32);
        acc = __builtin_amdgcn_mfma_f32_16x16x32_bf16(afr[kc], bfr, acc, 0, 0, 0);
      }
      int ccol = (nt & 1) * 16 + m16;   // 0..31 within head
      #pragma unroll
      for (int reg = 0; reg < 4; reg++){
        int row = mt * 16 + quad * 4 + reg;
        float v = acc[reg];
        if (mat == 0)      qs[(row * 32 + ccol) ^ ((row & 7) << 3)] = (__bf16)(v * qscale);
        else if (mat == 1) ks[(row * 32 + ccol) ^ ((row & 7) << 3)] = (__bf16)v;
        else               vs[(ccol * NN + row) ^ ((ccol & 7) << 3)] = (__bf16)v;
      }
    }
  }
  __syncthreads();

  // ---- Phase 2: attention, per-wave 16-row strips ----
  const float* brow_base = bias + (size_t)h * NN * NN;

  for (int s = 0; s < 6; s++){
    int strip = wv * 6 + s;
    int qrow = strip * 16 + m16;
    bf16x8 qf = *(const bf16x8*)(qs + ((qrow * 32 + quad * 8) ^ ((qrow & 7) << 3)));

    // Swapped QK^T with permuted K rows: sacc[2*kc+tb][reg] holds
    // S[q = strip*16+m16][k = 32*kc + 8*quad + 4*tb + reg]
    floatx4 sacc[24];
    __builtin_amdgcn_s_setprio(1);
    #pragma unroll
    for (int kc = 0; kc < 12; kc++){
      #pragma unroll
      for (int tb = 0; tb < 2; tb++){
        int krow = kc * 32 + ((m16 & 12) << 1) + tb * 4 + (m16 & 3);
        bf16x8 kf = *(const bf16x8*)(ks + ((krow * 32 + quad * 8) ^ ((krow & 7) << 3)));
        floatx4 z = {0.f, 0.f, 0.f, 0.f};
        sacc[kc * 2 + tb] = __builtin_amdgcn_mfma_f32_16x16x32_bf16(kf, qf, z, 0, 0, 0);
      }
    }
    __builtin_amdgcn_s_setprio(0);

    // bias + mask (float4 per reg-group) + row max
    float mx = -1e30f;
    #pragma unroll
    for (int kc = 0; kc < 12; kc++){
      #pragma unroll
      for (int tb = 0; tb < 2; tb++){
        int k0 = kc * 32 + quad * 8 + tb * 4;
        const float4 bb = *(const float4*)(brow_base + (size_t)qrow * NN + k0);
        const float4 mm = *(const float4*)(maskb + k0);
        floatx4 v = sacc[kc * 2 + tb];
        v[0] += bb.x + mm.x;
        v[1] += bb.y + mm.y;
        v[2] += bb.z + mm.z;
        v[3] += bb.w + mm.w;
        sacc[kc * 2 + tb] = v;
        mx = fmaxf(mx, fmaxf(fmaxf(v[0], v[1]), fmaxf(v[2], v[3])));
      }
    }
    mx = fmaxf(mx, __shfl_xor(mx, 16));
    mx = fmaxf(mx, __shfl_xor(mx, 32));

    // exp + row sum (in-lane, then combine the 4 quads)
    float sm = 0.f;
    #pragma unroll
    for (int kt = 0; kt < 24; kt++){
      floatx4 v = sacc[kt];
      #pragma unroll
      for (int reg = 0; reg < 4; reg++){
        float p = __expf(v[reg] - mx);
        sm += p;
        v[reg] = p;
      }
      sacc[kt] = v;
    }
    sm += __shfl_xor(sm, 16);
    sm += __shfl_xor(sm, 32);
    float inv = 1.0f / sm;

    // PV: pa built per-lane from sacc (already PV-A-fragment-ordered)
    floatx4 oacc[2] = {{0.f,0.f,0.f,0.f},{0.f,0.f,0.f,0.f}};
    #pragma unroll
    for (int kc = 0; kc < 12; kc++){
      floatx4 pa0 = sacc[kc * 2];
      floatx4 pa1 = sacc[kc * 2 + 1];
      bf16x8 pa;
      pa[0] = (__bf16)(pa0[0] * inv);
      pa[1] = (__bf16)(pa0[1] * inv);
      pa[2] = (__bf16)(pa0[2] * inv);
      pa[3] = (__bf16)(pa0[3] * inv);
      pa[4] = (__bf16)(pa1[0] * inv);
      pa[5] = (__bf16)(pa1[1] * inv);
      pa[6] = (__bf16)(pa1[2] * inv);
      pa[7] = (__bf16)(pa1[3] * inv);
      #pragma unroll
      for (int ct = 0; ct < 2; ct++){
        int c = ct * 16 + m16;
        bf16x8 vb = *(const bf16x8*)(vs + ((c * NN + kc * 32 + quad * 8) ^ ((c & 7) << 3)));
        oacc[ct] = __builtin_amdgcn_mfma_f32_16x16x32_bf16(pa, vb, oacc[ct], 0, 0, 0);
      }
    }

    #pragma unroll
    for (int ct = 0; ct < 2; ct++){
      #pragma unroll
      for (int reg = 0; reg < 4; reg++){
        int row = strip * 16 + quad * 4 + reg;
        wa[(size_t)(i * NN + row) * HCC + h * CH + ct * 16 + m16] =
            (__bf16)(oacc[ct][reg]);
      }
    }
  }
}

// Kernel C (MFMA): gate = sigmoid(Zn@Wg + gb); out = (gate*wa)@Wo + Zr + ob
// (Reverted to the proven R0 version.)
__global__ __launch_bounds__(256, 1) void out_kernel(
    const float* __restrict__ Zr, const __bf16* __restrict__ Zn,
    const __bf16* __restrict__ wa, const __bf16* __restrict__ WgT,
    const float* __restrict__ gb, const __bf16* __restrict__ WoT,
    const float* __restrict__ ob, float* __restrict__ out)
{
  __shared__ __align__(16) __bf16 wgs[128 * WSTRIDE];       // [h][d]
  __shared__ __align__(16) __bf16 wos[128 * WSTRIDE];       // [d][e]
  __shared__ __align__(16) __bf16 gsh[4][16 * WSTRIDE];     // per-wave G strip
  __shared__ float gbs[HCC], obs[DP];

  int t = threadIdx.x;
  int wv = t >> 6, lane = t & 63;
  int m16 = lane & 15, quad = lane >> 4;

  for (int idx = t * 8; idx < 128 * 128; idx += 256 * 8){
    int r = idx >> 7, c = idx & 127;
    *(bf16x8*)(wgs + r * WSTRIDE + c) = *(const bf16x8*)(WgT + idx);
    *(bf16x8*)(wos + r * WSTRIDE + c) = *(const bf16x8*)(WoT + idx);
  }
  if (t < 128){ gbs[t] = gb[t]; obs[t] = ob[t]; }
  __syncthreads();

  int mbase = blockIdx.x * 128;
  __bf16* gstrip = gsh[wv];

  for (int sp = 0; sp < 2; sp++){
    int row0 = mbase + (sp * 4 + wv) * 16;
    // gate GEMM: A from Zn rows, B from wgs
    bf16x8 afr[4];
    const __bf16* arow = Zn + (size_t)(row0 + m16) * DP + quad * 8;
    #pragma unroll
    for (int kc = 0; kc < 4; kc++) afr[kc] = *(const bf16x8*)(arow + kc * 32);
    #pragma unroll
    for (int nt = 0; nt < 8; nt++){
      floatx4 acc = {0.f, 0.f, 0.f, 0.f};
      #pragma unroll
      for (int kc = 0; kc < 4; kc++){
        bf16x8 bfr = *(const bf16x8*)(wgs + (nt * 16 + m16) * WSTRIDE + kc * 32 + quad * 8);
        acc = __builtin_amdgcn_mfma_f32_16x16x32_bf16(afr[kc], bfr, acc, 0, 0, 0);
      }
      int col = nt * 16 + m16;
      #pragma unroll
      for (int reg = 0; reg < 4; reg++){
        int row = row0 + quad * 4 + reg;
        float g = 1.0f / (1.0f + __expf(-(acc[reg] + gbs[col])));
        float w = b2f(wa[(size_t)row * HCC + col]);
        gstrip[(quad * 4 + reg) * WSTRIDE + col] = f2b(g * w);
      }
    }
    // out GEMM: A from gstrip (same wave — lockstep, compiler inserts lgkmcnt waits)
    bf16x8 gfr[4];
    #pragma unroll
    for (int kc = 0; kc < 4; kc++)
      gfr[kc] = *(const bf16x8*)(gstrip + m16 * WSTRIDE + kc * 32 + quad * 8);
    #pragma unroll
    for (int nt = 0; nt < 8; nt++){
      floatx4 acc = {0.f, 0.f, 0.f, 0.f};
      #pragma unroll
      for (int kc = 0; kc < 4; kc++){
        bf16x8 bfr = *(const bf16x8*)(wos + (nt * 16 + m16) * WSTRIDE + kc * 32 + quad * 8);
        acc = __builtin_amdgcn_mfma_f32_16x16x32_bf16(gfr[kc], bfr, acc, 0, 0, 0);
      }
      int col = nt * 16 + m16;
      #pragma unroll
      for (int reg = 0; reg < 4; reg++){
        int row = row0 + quad * 4 + reg;
        size_t off = (size_t)row * DP + col;
        out[off] = Zr[off] + acc[reg] + obs[col];
      }
    }
  }
}

extern "C" void kernel_launch(void* const* d_in, const int* in_sizes, int n_in,
                              void* d_out, int out_size, void* d_ws, size_t ws_size,
                              hipStream_t stream)
{
  const float* Zr   = (const float*)d_in[0];
  const float* Zm   = (const float*)d_in[1];
  const float* lnw  = (const float*)d_in[2];
  const float* lnb  = (const float*)d_in[3];
  const float* Wb   = (const float*)d_in[4];
  const float* Wqkv = (const float*)d_in[5];
  const float* Wg   = (const float*)d_in[6];
  const float* gb   = (const float*)d_in[7];
  const float* Wo   = (const float*)d_in[8];
  const float* ob   = (const float*)d_in[9];
  float* out = (float*)d_out;

  char* ws = (char*)d_ws;
  // ws: Zn bf16 | bias fp32 | wa bf16 | Wt bf16 | WgT bf16 | WoT bf16
  size_t off = 0;
  bf16*   Zn   = (bf16*)(ws + off);           off += (size_t)NN * NN * DP * 2;
  float*  bias = (float*)(ws + off);          off += (size_t)NHEAD * NN * NN * 4;
  bf16*   wa   = (bf16*)(ws + off);           off += (size_t)NN * NN * HCC * 2;
  __bf16* Wt   = (__bf16*)(ws + off);         off += (size_t)3 * HCC * DP * 2;
  __bf16* WgT  = (__bf16*)(ws + off);         off += (size_t)DP * HCC * 2;
  __bf16* WoT  = (__bf16*)(ws + off);         off += (size_t)HCC * DP * 2;

  wt_kernel<<<(3 * HCC * DP) / 256, 256, 0, stream>>>(Wqkv, Wt);
  wgo_kernel<<<(DP * HCC) / 256, 256, 0, stream>>>(Wg, Wo, WgT, WoT);
  ln_bias_kernel<<<NN * NN / 8, 256, 0, stream>>>(Zr, lnw, lnb, Wb, Zn, bias);
  attn_kernel<<<NN * NHEAD, 256, 0, stream>>>((const __bf16*)Zn, Wt, Zm, bias, (__bf16*)wa);
  out_kernel<<<NN * NN / 128, 256, 0, stream>>>(Zr, (const __bf16*)Zn, (const __bf16*)wa,
                                                WgT, gb, WoT, ob, out);
}

// Round 4
// 796.527 us; speedup vs baseline: 1.0044x; 1.0044x over previous
//
#include <hip/hip_runtime.h>
#include <hip/hip_bf16.h>

#define NN 384
#define DP 128
#define NHEAD 4
#define CH 32
#define HCC 128

typedef __hip_bfloat16 bf16;
typedef __bf16 bf16x8 __attribute__((ext_vector_type(8)));
typedef __bf16 bf16x4 __attribute__((ext_vector_type(4)));
typedef float floatx4 __attribute__((ext_vector_type(4)));

#define WSTRIDE 136   // weight/G-strip stride in bf16 elems (conflict-free b128)

__device__ __forceinline__ float b2f(bf16 x){ return __bfloat162float(x); }
__device__ __forceinline__ bf16 f2b(float x){ return __float2bfloat16(x); }

// Prep: Wt[col][d] = bf16(Wqkv[d][col]); col in [0,384), d in [0,128)
__global__ __launch_bounds__(256) void wt_kernel(
    const float* __restrict__ Wqkv, __bf16* __restrict__ Wt)
{
  int idx = blockIdx.x * 256 + threadIdx.x;   // 49152 total
  int d = idx / NN, col = idx - d * NN;
  Wt[col * DP + d] = (__bf16)Wqkv[idx];
}

// Prep: WgT[h][d] = Wg[d][h]; WoT[d][e] = Wo[e][d]  (both 128x128)
__global__ __launch_bounds__(256) void wgo_kernel(
    const float* __restrict__ Wg, const float* __restrict__ Wo,
    __bf16* __restrict__ WgT, __bf16* __restrict__ WoT)
{
  int idx = blockIdx.x * 256 + threadIdx.x;   // 16384 total
  int r = idx >> 7, c = idx & 127;
  WgT[idx] = (__bf16)Wg[c * 128 + r];
  WoT[idx] = (__bf16)Wo[c * 128 + r];
}

// Kernel A: LayerNorm + triangle bias. 32-lane group per position, float4 lanes.
__global__ __launch_bounds__(256) void ln_bias_kernel(
    const float* __restrict__ Zr, const float* __restrict__ lnw,
    const float* __restrict__ lnb, const float* __restrict__ Wb,
    bf16* __restrict__ Zn, float* __restrict__ bias)
{
  int t = threadIdx.x;
  int grp = t >> 5, lane32 = t & 31;
  int pos = blockIdx.x * 8 + grp;
  size_t base = (size_t)pos * DP;
  const float4 x = *(const float4*)(Zr + base + lane32 * 4);
  float s  = x.x + x.y + x.z + x.w;
  float s2 = x.x*x.x + x.y*x.y + x.z*x.z + x.w*x.w;
  #pragma unroll
  for (int m = 1; m < 32; m <<= 1){ s += __shfl_xor(s, m); s2 += __shfl_xor(s2, m); }
  float mean = s * (1.0f / DP);
  float var  = s2 * (1.0f / DP) - mean * mean;
  float rstd = rsqrtf(var + 1e-5f);
  const float4 w4 = *(const float4*)(lnw + lane32 * 4);
  const float4 b4 = *(const float4*)(lnb + lane32 * 4);
  float z0 = (x.x - mean) * rstd * w4.x + b4.x;
  float z1 = (x.y - mean) * rstd * w4.y + b4.y;
  float z2 = (x.z - mean) * rstd * w4.z + b4.z;
  float z3 = (x.w - mean) * rstd * w4.w + b4.w;
  bf16x4 zb = { (__bf16)z0, (__bf16)z1, (__bf16)z2, (__bf16)z3 };
  *(bf16x4*)((__bf16*)Zn + base + lane32 * 4) = zb;
  // bias partials: p[h] = sum_j z_j * Wb[(lane32*4+j)][h]
  const float4 wb0 = *(const float4*)(Wb + (lane32 * 4 + 0) * NHEAD);
  const float4 wb1 = *(const float4*)(Wb + (lane32 * 4 + 1) * NHEAD);
  const float4 wb2 = *(const float4*)(Wb + (lane32 * 4 + 2) * NHEAD);
  const float4 wb3 = *(const float4*)(Wb + (lane32 * 4 + 3) * NHEAD);
  float p0 = z0*wb0.x + z1*wb1.x + z2*wb2.x + z3*wb3.x;
  float p1 = z0*wb0.y + z1*wb1.y + z2*wb2.y + z3*wb3.y;
  float p2 = z0*wb0.z + z1*wb1.z + z2*wb2.z + z3*wb3.z;
  float p3 = z0*wb0.w + z1*wb1.w + z2*wb2.w + z3*wb3.w;
  #pragma unroll
  for (int m = 1; m < 32; m <<= 1){
    p0 += __shfl_xor(p0, m); p1 += __shfl_xor(p1, m);
    p2 += __shfl_xor(p2, m); p3 += __shfl_xor(p3, m);
  }
  if (lane32 == 0){
    bias[0 * NN * NN + pos] = p0;
    bias[1 * NN * NN + pos] = p1;
    bias[2 * NN * NN + pos] = p2;
    bias[3 * NN * NN + pos] = p3;
  }
}

// Kernel B: per (i, head): MFMA qkv projection + MFMA flash attention.
// In-register P (R3 structure), IDENTITY block mapping (R0):
//  - identity mapping h = bid&3 + XCD round-robin (bid%8) means each XCD
//    only ever runs ONE head -> its 590 KB bias slice stays L2-resident.
//    (R3's swizzle gave each XCD all 4 heads -> L2 thrash, FETCH 891 MB.)
//  - QK^T computed SWAPPED (mfma(kf, qf)) so each lane's S row is q = m16.
//  - K-tile rows loaded PERMUTED: A-row m sources K-row 8*(m>>2)+(m&3)+4*tb,
//    so lane (m16,quad) holds P[q=m16][k=32*kc+8*quad+j] — exactly the PV
//    A-fragment, built per-lane (no LDS round-trip, no cross-lane ops).
//  - bias/mask loads are float4; P normalized in-lane before pack.
// LDS = qs 24K + ks 24K + vs 24K + maskb 1.5K = 75.3 KB -> 2 blocks/CU.
__global__ __launch_bounds__(256, 2) void attn_kernel(
    const __bf16* __restrict__ Zn, const __bf16* __restrict__ Wt,
    const float* __restrict__ Zm, const float* __restrict__ bias,
    __bf16* __restrict__ wa)
{
  __shared__ __align__(128) __bf16 qs[NN * 32];   // q: [row][c] swizzled
  __shared__ __align__(128) __bf16 ks[NN * 32];   // k: [row][c] swizzled
  __shared__ __align__(128) __bf16 vs[CH * NN];   // v^T: [c][row] swizzled
  __shared__ __align__(16) float maskb[NN];

  int i = blockIdx.x >> 2;
  int h = blockIdx.x & 3;
  int t = threadIdx.x;
  int wv = t >> 6;
  int lane = t & 63;
  int m16 = lane & 15;       // low-16 lane id
  int quad = lane >> 4;      // 0..3

  for (int k = t; k < NN; k += 256)
    maskb[k] = (Zm[(size_t)i * NN + k] - 1.0f) * 1e9f;

  const float qscale = 0.17677669529663687f; // 1/sqrt(32)

  // ---- Phase 1: qkv projection via MFMA (identical to R0, swizzled stores) ----
  for (int mt = wv * 6; mt < wv * 6 + 6; mt++){
    bf16x8 afr[4];
    const __bf16* arow = Zn + (size_t)(i * NN + mt * 16 + m16) * DP + quad * 8;
    #pragma unroll
    for (int kc = 0; kc < 4; kc++) afr[kc] = *(const bf16x8*)(arow + kc * 32);
    #pragma unroll
    for (int nt = 0; nt < 6; nt++){
      int mat = nt >> 1;
      int colbase = mat * HCC + h * CH + (nt & 1) * 16;
      const __bf16* brow = Wt + (size_t)(colbase + m16) * DP + quad * 8;
      floatx4 acc = {0.f, 0.f, 0.f, 0.f};
      #pragma unroll
      for (int kc = 0; kc < 4; kc++){
        bf16x8 bfr = *(const bf16x8*)(brow + kc * 32);
        acc = __builtin_amdgcn_mfma_f32_16x16x32_bf16(afr[kc], bfr, acc, 0, 0, 0);
      }
      int ccol = (nt & 1) * 16 + m16;   // 0..31 within head
      #pragma unroll
      for (int reg = 0; reg < 4; reg++){
        int row = mt * 16 + quad * 4 + reg;
        float v = acc[reg];
        if (mat == 0)      qs[(row * 32 + ccol) ^ ((row & 7) << 3)] = (__bf16)(v * qscale);
        else if (mat == 1) ks[(row * 32 + ccol) ^ ((row & 7) << 3)] = (__bf16)v;
        else               vs[(ccol * NN + row) ^ ((ccol & 7) << 3)] = (__bf16)v;
      }
    }
  }
  __syncthreads();

  // ---- Phase 2: attention, per-wave 16-row strips ----
  const float* brow_base = bias + (size_t)h * NN * NN;

  for (int s = 0; s < 6; s++){
    int strip = wv * 6 + s;
    int qrow = strip * 16 + m16;
    bf16x8 qf = *(const bf16x8*)(qs + ((qrow * 32 + quad * 8) ^ ((qrow & 7) << 3)));

    // Swapped QK^T with permuted K rows: sacc[2*kc+tb][reg] holds
    // S[q = strip*16+m16][k = 32*kc + 8*quad + 4*tb + reg]
    floatx4 sacc[24];
    __builtin_amdgcn_s_setprio(1);
    #pragma unroll
    for (int kc = 0; kc < 12; kc++){
      #pragma unroll
      for (int tb = 0; tb < 2; tb++){
        int krow = kc * 32 + ((m16 & 12) << 1) + tb * 4 + (m16 & 3);
        bf16x8 kf = *(const bf16x8*)(ks + ((krow * 32 + quad * 8) ^ ((krow & 7) << 3)));
        floatx4 z = {0.f, 0.f, 0.f, 0.f};
        sacc[kc * 2 + tb] = __builtin_amdgcn_mfma_f32_16x16x32_bf16(kf, qf, z, 0, 0, 0);
      }
    }
    __builtin_amdgcn_s_setprio(0);

    // bias + mask (float4 per reg-group) + row max
    float mx = -1e30f;
    #pragma unroll
    for (int kc = 0; kc < 12; kc++){
      #pragma unroll
      for (int tb = 0; tb < 2; tb++){
        int k0 = kc * 32 + quad * 8 + tb * 4;
        const float4 bb = *(const float4*)(brow_base + (size_t)qrow * NN + k0);
        const float4 mm = *(const float4*)(maskb + k0);
        floatx4 v = sacc[kc * 2 + tb];
        v[0] += bb.x + mm.x;
        v[1] += bb.y + mm.y;
        v[2] += bb.z + mm.z;
        v[3] += bb.w + mm.w;
        sacc[kc * 2 + tb] = v;
        mx = fmaxf(mx, fmaxf(fmaxf(v[0], v[1]), fmaxf(v[2], v[3])));
      }
    }
    mx = fmaxf(mx, __shfl_xor(mx, 16));
    mx = fmaxf(mx, __shfl_xor(mx, 32));

    // exp + row sum (in-lane, then combine the 4 quads)
    float sm = 0.f;
    #pragma unroll
    for (int kt = 0; kt < 24; kt++){
      floatx4 v = sacc[kt];
      #pragma unroll
      for (int reg = 0; reg < 4; reg++){
        float p = __expf(v[reg] - mx);
        sm += p;
        v[reg] = p;
      }
      sacc[kt] = v;
    }
    sm += __shfl_xor(sm, 16);
    sm += __shfl_xor(sm, 32);
    float inv = 1.0f / sm;

    // PV: pa built per-lane from sacc (already PV-A-fragment-ordered)
    floatx4 oacc[2] = {{0.f,0.f,0.f,0.f},{0.f,0.f,0.f,0.f}};
    #pragma unroll
    for (int kc = 0; kc < 12; kc++){
      floatx4 pa0 = sacc[kc * 2];
      floatx4 pa1 = sacc[kc * 2 + 1];
      bf16x8 pa;
      pa[0] = (__bf16)(pa0[0] * inv);
      pa[1] = (__bf16)(pa0[1] * inv);
      pa[2] = (__bf16)(pa0[2] * inv);
      pa[3] = (__bf16)(pa0[3] * inv);
      pa[4] = (__bf16)(pa1[0] * inv);
      pa[5] = (__bf16)(pa1[1] * inv);
      pa[6] = (__bf16)(pa1[2] * inv);
      pa[7] = (__bf16)(pa1[3] * inv);
      #pragma unroll
      for (int ct = 0; ct < 2; ct++){
        int c = ct * 16 + m16;
        bf16x8 vb = *(const bf16x8*)(vs + ((c * NN + kc * 32 + quad * 8) ^ ((c & 7) << 3)));
        oacc[ct] = __builtin_amdgcn_mfma_f32_16x16x32_bf16(pa, vb, oacc[ct], 0, 0, 0);
      }
    }

    #pragma unroll
    for (int ct = 0; ct < 2; ct++){
      #pragma unroll
      for (int reg = 0; reg < 4; reg++){
        int row = strip * 16 + quad * 4 + reg;
        wa[(size_t)(i * NN + row) * HCC + h * CH + ct * 16 + m16] =
            (__bf16)(oacc[ct][reg]);
      }
    }
  }
}

// Kernel C (MFMA): gate = sigmoid(Zn@Wg + gb); out = (gate*wa)@Wo + Zr + ob
// (Proven R0 version.)
__global__ __launch_bounds__(256, 1) void out_kernel(
    const float* __restrict__ Zr, const __bf16* __restrict__ Zn,
    const __bf16* __restrict__ wa, const __bf16* __restrict__ WgT,
    const float* __restrict__ gb, const __bf16* __restrict__ WoT,
    const float* __restrict__ ob, float* __restrict__ out)
{
  __shared__ __align__(16) __bf16 wgs[128 * WSTRIDE];       // [h][d]
  __shared__ __align__(16) __bf16 wos[128 * WSTRIDE];       // [d][e]
  __shared__ __align__(16) __bf16 gsh[4][16 * WSTRIDE];     // per-wave G strip
  __shared__ float gbs[HCC], obs[DP];

  int t = threadIdx.x;
  int wv = t >> 6, lane = t & 63;
  int m16 = lane & 15, quad = lane >> 4;

  for (int idx = t * 8; idx < 128 * 128; idx += 256 * 8){
    int r = idx >> 7, c = idx & 127;
    *(bf16x8*)(wgs + r * WSTRIDE + c) = *(const bf16x8*)(WgT + idx);
    *(bf16x8*)(wos + r * WSTRIDE + c) = *(const bf16x8*)(WoT + idx);
  }
  if (t < 128){ gbs[t] = gb[t]; obs[t] = ob[t]; }
  __syncthreads();

  int mbase = blockIdx.x * 128;
  __bf16* gstrip = gsh[wv];

  for (int sp = 0; sp < 2; sp++){
    int row0 = mbase + (sp * 4 + wv) * 16;
    // gate GEMM: A from Zn rows, B from wgs
    bf16x8 afr[4];
    const __bf16* arow = Zn + (size_t)(row0 + m16) * DP + quad * 8;
    #pragma unroll
    for (int kc = 0; kc < 4; kc++) afr[kc] = *(const bf16x8*)(arow + kc * 32);
    #pragma unroll
    for (int nt = 0; nt < 8; nt++){
      floatx4 acc = {0.f, 0.f, 0.f, 0.f};
      #pragma unroll
      for (int kc = 0; kc < 4; kc++){
        bf16x8 bfr = *(const bf16x8*)(wgs + (nt * 16 + m16) * WSTRIDE + kc * 32 + quad * 8);
        acc = __builtin_amdgcn_mfma_f32_16x16x32_bf16(afr[kc], bfr, acc, 0, 0, 0);
      }
      int col = nt * 16 + m16;
      #pragma unroll
      for (int reg = 0; reg < 4; reg++){
        int row = row0 + quad * 4 + reg;
        float g = 1.0f / (1.0f + __expf(-(acc[reg] + gbs[col])));
        float w = b2f(wa[(size_t)row * HCC + col]);
        gstrip[(quad * 4 + reg) * WSTRIDE + col] = f2b(g * w);
      }
    }
    // out GEMM: A from gstrip (same wave — lockstep, compiler inserts lgkmcnt waits)
    bf16x8 gfr[4];
    #pragma unroll
    for (int kc = 0; kc < 4; kc++)
      gfr[kc] = *(const bf16x8*)(gstrip + m16 * WSTRIDE + kc * 32 + quad * 8);
    #pragma unroll
    for (int nt = 0; nt < 8; nt++){
      floatx4 acc = {0.f, 0.f, 0.f, 0.f};
      #pragma unroll
      for (int kc = 0; kc < 4; kc++){
        bf16x8 bfr = *(const bf16x8*)(wos + (nt * 16 + m16) * WSTRIDE + kc * 32 + quad * 8);
        acc = __builtin_amdgcn_mfma_f32_16x16x32_bf16(gfr[kc], bfr, acc, 0, 0, 0);
      }
      int col = nt * 16 + m16;
      #pragma unroll
      for (int reg = 0; reg < 4; reg++){
        int row = row0 + quad * 4 + reg;
        size_t off = (size_t)row * DP + col;
        out[off] = Zr[off] + acc[reg] + obs[col];
      }
    }
  }
}

extern "C" void kernel_launch(void* const* d_in, const int* in_sizes, int n_in,
                              void* d_out, int out_size, void* d_ws, size_t ws_size,
                              hipStream_t stream)
{
  const float* Zr   = (const float*)d_in[0];
  const float* Zm   = (const float*)d_in[1];
  const float* lnw  = (const float*)d_in[2];
  const float* lnb  = (const float*)d_in[3];
  const float* Wb   = (const float*)d_in[4];
  const float* Wqkv = (const float*)d_in[5];
  const float* Wg   = (const float*)d_in[6];
  const float* gb   = (const float*)d_in[7];
  const float* Wo   = (const float*)d_in[8];
  const float* ob   = (const float*)d_in[9];
  float* out = (float*)d_out;

  char* ws = (char*)d_ws;
  // ws: Zn bf16 | bias fp32 | wa bf16 | Wt bf16 | WgT bf16 | WoT bf16
  size_t off = 0;
  bf16*   Zn   = (bf16*)(ws + off);           off += (size_t)NN * NN * DP * 2;
  float*  bias = (float*)(ws + off);          off += (size_t)NHEAD * NN * NN * 4;
  bf16*   wa   = (bf16*)(ws + off);           off += (size_t)NN * NN * HCC * 2;
  __bf16* Wt   = (__bf16*)(ws + off);         off += (size_t)3 * HCC * DP * 2;
  __bf16* WgT  = (__bf16*)(ws + off);         off += (size_t)DP * HCC * 2;
  __bf16* WoT  = (__bf16*)(ws + off);         off += (size_t)HCC * DP * 2;

  wt_kernel<<<(3 * HCC * DP) / 256, 256, 0, stream>>>(Wqkv, Wt);
  wgo_kernel<<<(DP * HCC) / 256, 256, 0, stream>>>(Wg, Wo, WgT, WoT);
  ln_bias_kernel<<<NN * NN / 8, 256, 0, stream>>>(Zr, lnw, lnb, Wb, Zn, bias);
  attn_kernel<<<NN * NHEAD, 256, 0, stream>>>((const __bf16*)Zn, Wt, Zm, bias, (__bf16*)wa);
  out_kernel<<<NN * NN / 128, 256, 0, stream>>>(Zr, (const __bf16*)Zn, (const __bf16*)wa,
                                                WgT, gb, WoT, ob, out);
}

// Round 5
// 676.278 us; speedup vs baseline: 1.1830x; 1.1778x over previous
//
#include <hip/hip_runtime.h>
#include <hip/hip_bf16.h>

#define NN 384
#define DP 128
#define NHEAD 4
#define CH 32
#define HCC 128

typedef __hip_bfloat16 bf16;
typedef __bf16 bf16x8 __attribute__((ext_vector_type(8)));
typedef __bf16 bf16x4 __attribute__((ext_vector_type(4)));
typedef float floatx4 __attribute__((ext_vector_type(4)));

#define WSTRIDE 136   // weight/G-strip stride in bf16 elems (conflict-free b128)

__device__ __forceinline__ float b2f(bf16 x){ return __bfloat162float(x); }
__device__ __forceinline__ bf16 f2b(float x){ return __float2bfloat16(x); }

// Prep: Wt[col][d] = bf16(Wqkv[d][col]); col in [0,384), d in [0,128)
__global__ __launch_bounds__(256) void wt_kernel(
    const float* __restrict__ Wqkv, __bf16* __restrict__ Wt)
{
  int idx = blockIdx.x * 256 + threadIdx.x;   // 49152 total
  int d = idx / NN, col = idx - d * NN;
  Wt[col * DP + d] = (__bf16)Wqkv[idx];
}

// Prep: WgT[h][d] = Wg[d][h]; WoT[d][e] = Wo[e][d]  (both 128x128)
__global__ __launch_bounds__(256) void wgo_kernel(
    const float* __restrict__ Wg, const float* __restrict__ Wo,
    __bf16* __restrict__ WgT, __bf16* __restrict__ WoT)
{
  int idx = blockIdx.x * 256 + threadIdx.x;   // 16384 total
  int r = idx >> 7, c = idx & 127;
  WgT[idx] = (__bf16)Wg[c * 128 + r];
  WoT[idx] = (__bf16)Wo[c * 128 + r];
}

// Kernel A: LayerNorm + triangle bias. 32-lane group per position, float4 lanes.
__global__ __launch_bounds__(256) void ln_bias_kernel(
    const float* __restrict__ Zr, const float* __restrict__ lnw,
    const float* __restrict__ lnb, const float* __restrict__ Wb,
    bf16* __restrict__ Zn, float* __restrict__ bias)
{
  int t = threadIdx.x;
  int grp = t >> 5, lane32 = t & 31;
  int pos = blockIdx.x * 8 + grp;
  size_t base = (size_t)pos * DP;
  const float4 x = *(const float4*)(Zr + base + lane32 * 4);
  float s  = x.x + x.y + x.z + x.w;
  float s2 = x.x*x.x + x.y*x.y + x.z*x.z + x.w*x.w;
  #pragma unroll
  for (int m = 1; m < 32; m <<= 1){ s += __shfl_xor(s, m); s2 += __shfl_xor(s2, m); }
  float mean = s * (1.0f / DP);
  float var  = s2 * (1.0f / DP) - mean * mean;
  float rstd = rsqrtf(var + 1e-5f);
  const float4 w4 = *(const float4*)(lnw + lane32 * 4);
  const float4 b4 = *(const float4*)(lnb + lane32 * 4);
  float z0 = (x.x - mean) * rstd * w4.x + b4.x;
  float z1 = (x.y - mean) * rstd * w4.y + b4.y;
  float z2 = (x.z - mean) * rstd * w4.z + b4.z;
  float z3 = (x.w - mean) * rstd * w4.w + b4.w;
  bf16x4 zb = { (__bf16)z0, (__bf16)z1, (__bf16)z2, (__bf16)z3 };
  *(bf16x4*)((__bf16*)Zn + base + lane32 * 4) = zb;
  // bias partials: p[h] = sum_j z_j * Wb[(lane32*4+j)][h]
  const float4 wb0 = *(const float4*)(Wb + (lane32 * 4 + 0) * NHEAD);
  const float4 wb1 = *(const float4*)(Wb + (lane32 * 4 + 1) * NHEAD);
  const float4 wb2 = *(const float4*)(Wb + (lane32 * 4 + 2) * NHEAD);
  const float4 wb3 = *(const float4*)(Wb + (lane32 * 4 + 3) * NHEAD);
  float p0 = z0*wb0.x + z1*wb1.x + z2*wb2.x + z3*wb3.x;
  float p1 = z0*wb0.y + z1*wb1.y + z2*wb2.y + z3*wb3.y;
  float p2 = z0*wb0.z + z1*wb1.z + z2*wb2.z + z3*wb3.z;
  float p3 = z0*wb0.w + z1*wb1.w + z2*wb2.w + z3*wb3.w;
  #pragma unroll
  for (int m = 1; m < 32; m <<= 1){
    p0 += __shfl_xor(p0, m); p1 += __shfl_xor(p1, m);
    p2 += __shfl_xor(p2, m); p3 += __shfl_xor(p3, m);
  }
  if (lane32 == 0){
    bias[0 * NN * NN + pos] = p0;
    bias[1 * NN * NN + pos] = p1;
    bias[2 * NN * NN + pos] = p2;
    bias[3 * NN * NN + pos] = p3;
  }
}

// Kernel B: per (i, head): MFMA qkv projection + MFMA flash attention.
// In-register P with ONLINE softmax over two 192-col halves:
//  - R3/R4 kept sacc[24] (96 f32) live from QK through PV -> scratch spill
//    (WRITE_SIZE 37->318 MB, FETCH 82->925 MB). Halving to sacc[12] per
//    half and rescaling oacc flash-style keeps peak liveness ~100 regs.
//  - QK^T computed SWAPPED (mfma(kf, qf)) so each lane's S row is q = m16.
//  - K-tile rows loaded PERMUTED: A-row m sources K-row 8*(m>>2)+(m&3)+4*tb,
//    so lane (m16,quad) holds P[q=m16][k=32*kc+8*quad+j] — exactly the PV
//    A-fragment, built per-lane (no LDS round-trip, no cross-lane ops).
//  - oacc rows are q=quad*4+reg while the lane's softmax row is q=m16:
//    rescale/normalize factors are fetched with 4 __shfl's (quad-uniform).
// LDS = qs 24K + ks 24K + vs 24K + maskb 1.5K = 75.3 KB -> 2 blocks/CU.
__global__ __launch_bounds__(256, 2) void attn_kernel(
    const __bf16* __restrict__ Zn, const __bf16* __restrict__ Wt,
    const float* __restrict__ Zm, const float* __restrict__ bias,
    __bf16* __restrict__ wa)
{
  __shared__ __align__(128) __bf16 qs[NN * 32];   // q: [row][c] swizzled
  __shared__ __align__(128) __bf16 ks[NN * 32];   // k: [row][c] swizzled
  __shared__ __align__(128) __bf16 vs[CH * NN];   // v^T: [c][row] swizzled
  __shared__ __align__(16) float maskb[NN];

  int i = blockIdx.x >> 2;
  int h = blockIdx.x & 3;
  int t = threadIdx.x;
  int wv = t >> 6;
  int lane = t & 63;
  int m16 = lane & 15;       // low-16 lane id
  int quad = lane >> 4;      // 0..3

  for (int k = t; k < NN; k += 256)
    maskb[k] = (Zm[(size_t)i * NN + k] - 1.0f) * 1e9f;

  const float qscale = 0.17677669529663687f; // 1/sqrt(32)

  // ---- Phase 1: qkv projection via MFMA (identical to R0, swizzled stores) ----
  for (int mt = wv * 6; mt < wv * 6 + 6; mt++){
    bf16x8 afr[4];
    const __bf16* arow = Zn + (size_t)(i * NN + mt * 16 + m16) * DP + quad * 8;
    #pragma unroll
    for (int kc = 0; kc < 4; kc++) afr[kc] = *(const bf16x8*)(arow + kc * 32);
    #pragma unroll
    for (int nt = 0; nt < 6; nt++){
      int mat = nt >> 1;
      int colbase = mat * HCC + h * CH + (nt & 1) * 16;
      const __bf16* brow = Wt + (size_t)(colbase + m16) * DP + quad * 8;
      floatx4 acc = {0.f, 0.f, 0.f, 0.f};
      #pragma unroll
      for (int kc = 0; kc < 4; kc++){
        bf16x8 bfr = *(const bf16x8*)(brow + kc * 32);
        acc = __builtin_amdgcn_mfma_f32_16x16x32_bf16(afr[kc], bfr, acc, 0, 0, 0);
      }
      int ccol = (nt & 1) * 16 + m16;   // 0..31 within head
      #pragma unroll
      for (int reg = 0; reg < 4; reg++){
        int row = mt * 16 + quad * 4 + reg;
        float v = acc[reg];
        if (mat == 0)      qs[(row * 32 + ccol) ^ ((row & 7) << 3)] = (__bf16)(v * qscale);
        else if (mat == 1) ks[(row * 32 + ccol) ^ ((row & 7) << 3)] = (__bf16)v;
        else               vs[(ccol * NN + row) ^ ((ccol & 7) << 3)] = (__bf16)v;
      }
    }
  }
  __syncthreads();

  // ---- Phase 2: attention, per-wave 16-row strips, online softmax ----
  const float* brow_base = bias + (size_t)h * NN * NN;

  for (int s = 0; s < 6; s++){
    int strip = wv * 6 + s;
    int qrow = strip * 16 + m16;
    bf16x8 qf = *(const bf16x8*)(qs + ((qrow * 32 + quad * 8) ^ ((qrow & 7) << 3)));

    float m_run = -1e30f;
    float sm = 0.f;
    floatx4 oacc[2] = {{0.f,0.f,0.f,0.f},{0.f,0.f,0.f,0.f}};

    #pragma unroll
    for (int half = 0; half < 2; half++){
      // QK^T (swapped, permuted K rows): sacc[2*kc2+tb][reg] holds
      // S[q=m16][k = 32*(half*6+kc2) + 8*quad + 4*tb + reg]
      floatx4 sacc[12];
      __builtin_amdgcn_s_setprio(1);
      #pragma unroll
      for (int kc2 = 0; kc2 < 6; kc2++){
        int kc = half * 6 + kc2;
        #pragma unroll
        for (int tb = 0; tb < 2; tb++){
          int krow = kc * 32 + ((m16 & 12) << 1) + tb * 4 + (m16 & 3);
          bf16x8 kf = *(const bf16x8*)(ks + ((krow * 32 + quad * 8) ^ ((krow & 7) << 3)));
          floatx4 z = {0.f, 0.f, 0.f, 0.f};
          sacc[kc2 * 2 + tb] = __builtin_amdgcn_mfma_f32_16x16x32_bf16(kf, qf, z, 0, 0, 0);
        }
      }
      __builtin_amdgcn_s_setprio(0);

      // bias + mask (float4 per reg-group) + local max
      float mx = -1e30f;
      #pragma unroll
      for (int kc2 = 0; kc2 < 6; kc2++){
        int kc = half * 6 + kc2;
        #pragma unroll
        for (int tb = 0; tb < 2; tb++){
          int k0 = kc * 32 + quad * 8 + tb * 4;
          const float4 bb = *(const float4*)(brow_base + (size_t)qrow * NN + k0);
          const float4 mm = *(const float4*)(maskb + k0);
          floatx4 v = sacc[kc2 * 2 + tb];
          v[0] += bb.x + mm.x;
          v[1] += bb.y + mm.y;
          v[2] += bb.z + mm.z;
          v[3] += bb.w + mm.w;
          sacc[kc2 * 2 + tb] = v;
          mx = fmaxf(mx, fmaxf(fmaxf(v[0], v[1]), fmaxf(v[2], v[3])));
        }
      }
      mx = fmaxf(mx, __shfl_xor(mx, 16));
      mx = fmaxf(mx, __shfl_xor(mx, 32));

      float m_new = fmaxf(m_run, mx);
      float scale = __expf(m_run - m_new);   // half 0: exp(-inf) = 0, oacc is 0
      m_run = m_new;
      sm *= scale;
      // redistribute scale to this lane's oacc rows (q = quad*4+reg);
      // scale is quad-uniform, so source lanes 0..15 cover all rows.
      float sc0 = __shfl(scale, quad * 4 + 0);
      float sc1 = __shfl(scale, quad * 4 + 1);
      float sc2 = __shfl(scale, quad * 4 + 2);
      float sc3 = __shfl(scale, quad * 4 + 3);
      #pragma unroll
      for (int ct = 0; ct < 2; ct++){
        oacc[ct][0] *= sc0; oacc[ct][1] *= sc1;
        oacc[ct][2] *= sc2; oacc[ct][3] *= sc3;
      }

      // exp + row-sum + PV (sacc dies here, inside the half)
      #pragma unroll
      for (int kc2 = 0; kc2 < 6; kc2++){
        int kc = half * 6 + kc2;
        floatx4 p0 = sacc[kc2 * 2];
        floatx4 p1 = sacc[kc2 * 2 + 1];
        bf16x8 pa;
        #pragma unroll
        for (int r = 0; r < 4; r++){
          float e0 = __expf(p0[r] - m_run);
          float e1 = __expf(p1[r] - m_run);
          sm += e0 + e1;
          pa[r] = (__bf16)e0;
          pa[r + 4] = (__bf16)e1;
        }
        #pragma unroll
        for (int ct = 0; ct < 2; ct++){
          int c = ct * 16 + m16;
          bf16x8 vb = *(const bf16x8*)(vs + ((c * NN + kc * 32 + quad * 8) ^ ((c & 7) << 3)));
          oacc[ct] = __builtin_amdgcn_mfma_f32_16x16x32_bf16(pa, vb, oacc[ct], 0, 0, 0);
        }
      }
    }

    sm += __shfl_xor(sm, 16);
    sm += __shfl_xor(sm, 32);
    float inv = 1.0f / sm;
    float iv0 = __shfl(inv, quad * 4 + 0);
    float iv1 = __shfl(inv, quad * 4 + 1);
    float iv2 = __shfl(inv, quad * 4 + 2);
    float iv3 = __shfl(inv, quad * 4 + 3);
    float iv[4] = {iv0, iv1, iv2, iv3};
    #pragma unroll
    for (int ct = 0; ct < 2; ct++){
      #pragma unroll
      for (int reg = 0; reg < 4; reg++){
        int row = strip * 16 + quad * 4 + reg;
        wa[(size_t)(i * NN + row) * HCC + h * CH + ct * 16 + m16] =
            (__bf16)(oacc[ct][reg] * iv[reg]);
      }
    }
  }
}

// Kernel C (MFMA): gate = sigmoid(Zn@Wg + gb); out = (gate*wa)@Wo + Zr + ob
// (Proven R0 version.)
__global__ __launch_bounds__(256, 1) void out_kernel(
    const float* __restrict__ Zr, const __bf16* __restrict__ Zn,
    const __bf16* __restrict__ wa, const __bf16* __restrict__ WgT,
    const float* __restrict__ gb, const __bf16* __restrict__ WoT,
    const float* __restrict__ ob, float* __restrict__ out)
{
  __shared__ __align__(16) __bf16 wgs[128 * WSTRIDE];       // [h][d]
  __shared__ __align__(16) __bf16 wos[128 * WSTRIDE];       // [d][e]
  __shared__ __align__(16) __bf16 gsh[4][16 * WSTRIDE];     // per-wave G strip
  __shared__ float gbs[HCC], obs[DP];

  int t = threadIdx.x;
  int wv = t >> 6, lane = t & 63;
  int m16 = lane & 15, quad = lane >> 4;

  for (int idx = t * 8; idx < 128 * 128; idx += 256 * 8){
    int r = idx >> 7, c = idx & 127;
    *(bf16x8*)(wgs + r * WSTRIDE + c) = *(const bf16x8*)(WgT + idx);
    *(bf16x8*)(wos + r * WSTRIDE + c) = *(const bf16x8*)(WoT + idx);
  }
  if (t < 128){ gbs[t] = gb[t]; obs[t] = ob[t]; }
  __syncthreads();

  int mbase = blockIdx.x * 128;
  __bf16* gstrip = gsh[wv];

  for (int sp = 0; sp < 2; sp++){
    int row0 = mbase + (sp * 4 + wv) * 16;
    // gate GEMM: A from Zn rows, B from wgs
    bf16x8 afr[4];
    const __bf16* arow = Zn + (size_t)(row0 + m16) * DP + quad * 8;
    #pragma unroll
    for (int kc = 0; kc < 4; kc++) afr[kc] = *(const bf16x8*)(arow + kc * 32);
    #pragma unroll
    for (int nt = 0; nt < 8; nt++){
      floatx4 acc = {0.f, 0.f, 0.f, 0.f};
      #pragma unroll
      for (int kc = 0; kc < 4; kc++){
        bf16x8 bfr = *(const bf16x8*)(wgs + (nt * 16 + m16) * WSTRIDE + kc * 32 + quad * 8);
        acc = __builtin_amdgcn_mfma_f32_16x16x32_bf16(afr[kc], bfr, acc, 0, 0, 0);
      }
      int col = nt * 16 + m16;
      #pragma unroll
      for (int reg = 0; reg < 4; reg++){
        int row = row0 + quad * 4 + reg;
        float g = 1.0f / (1.0f + __expf(-(acc[reg] + gbs[col])));
        float w = b2f(wa[(size_t)row * HCC + col]);
        gstrip[(quad * 4 + reg) * WSTRIDE + col] = f2b(g * w);
      }
    }
    // out GEMM: A from gstrip (same wave — lockstep, compiler inserts lgkmcnt waits)
    bf16x8 gfr[4];
    #pragma unroll
    for (int kc = 0; kc < 4; kc++)
      gfr[kc] = *(const bf16x8*)(gstrip + m16 * WSTRIDE + kc * 32 + quad * 8);
    #pragma unroll
    for (int nt = 0; nt < 8; nt++){
      floatx4 acc = {0.f, 0.f, 0.f, 0.f};
      #pragma unroll
      for (int kc = 0; kc < 4; kc++){
        bf16x8 bfr = *(const bf16x8*)(wos + (nt * 16 + m16) * WSTRIDE + kc * 32 + quad * 8);
        acc = __builtin_amdgcn_mfma_f32_16x16x32_bf16(gfr[kc], bfr, acc, 0, 0, 0);
      }
      int col = nt * 16 + m16;
      #pragma unroll
      for (int reg = 0; reg < 4; reg++){
        int row = row0 + quad * 4 + reg;
        size_t off = (size_t)row * DP + col;
        out[off] = Zr[off] + acc[reg] + obs[col];
      }
    }
  }
}

extern "C" void kernel_launch(void* const* d_in, const int* in_sizes, int n_in,
                              void* d_out, int out_size, void* d_ws, size_t ws_size,
                              hipStream_t stream)
{
  const float* Zr   = (const float*)d_in[0];
  const float* Zm   = (const float*)d_in[1];
  const float* lnw  = (const float*)d_in[2];
  const float* lnb  = (const float*)d_in[3];
  const float* Wb   = (const float*)d_in[4];
  const float* Wqkv = (const float*)d_in[5];
  const float* Wg   = (const float*)d_in[6];
  const float* gb   = (const float*)d_in[7];
  const float* Wo   = (const float*)d_in[8];
  const float* ob   = (const float*)d_in[9];
  float* out = (float*)d_out;

  char* ws = (char*)d_ws;
  // ws: Zn bf16 | bias fp32 | wa bf16 | Wt bf16 | WgT bf16 | WoT bf16
  size_t off = 0;
  bf16*   Zn   = (bf16*)(ws + off);           off += (size_t)NN * NN * DP * 2;
  float*  bias = (float*)(ws + off);          off += (size_t)NHEAD * NN * NN * 4;
  bf16*   wa   = (bf16*)(ws + off);           off += (size_t)NN * NN * HCC * 2;
  __bf16* Wt   = (__bf16*)(ws + off);         off += (size_t)3 * HCC * DP * 2;
  __bf16* WgT  = (__bf16*)(ws + off);         off += (size_t)DP * HCC * 2;
  __bf16* WoT  = (__bf16*)(ws + off);         off += (size_t)HCC * DP * 2;

  wt_kernel<<<(3 * HCC * DP) / 256, 256, 0, stream>>>(Wqkv, Wt);
  wgo_kernel<<<(DP * HCC) / 256, 256, 0, stream>>>(Wg, Wo, WgT, WoT);
  ln_bias_kernel<<<NN * NN / 8, 256, 0, stream>>>(Zr, lnw, lnb, Wb, Zn, bias);
  attn_kernel<<<NN * NHEAD, 256, 0, stream>>>((const __bf16*)Zn, Wt, Zm, bias, (__bf16*)wa);
  out_kernel<<<NN * NN / 128, 256, 0, stream>>>(Zr, (const __bf16*)Zn, (const __bf16*)wa,
                                                WgT, gb, WoT, ob, out);
}

// Round 6
// 586.423 us; speedup vs baseline: 1.3642x; 1.1532x over previous
//
#include <hip/hip_runtime.h>
#include <hip/hip_bf16.h>

#define NN 384
#define DP 128
#define NHEAD 4
#define CH 32
#define HCC 128

typedef __hip_bfloat16 bf16;
typedef __bf16 bf16x8 __attribute__((ext_vector_type(8)));
typedef __bf16 bf16x4 __attribute__((ext_vector_type(4)));
typedef float floatx4 __attribute__((ext_vector_type(4)));

#define WSTRIDE 136   // weight/G-strip stride in bf16 elems (conflict-free b128)

__device__ __forceinline__ float b2f(bf16 x){ return __bfloat162float(x); }
__device__ __forceinline__ bf16 f2b(float x){ return __float2bfloat16(x); }

// Prep: Wt[col][d] = bf16(Wqkv[d][col]); col in [0,384), d in [0,128)
__global__ __launch_bounds__(256) void wt_kernel(
    const float* __restrict__ Wqkv, __bf16* __restrict__ Wt)
{
  int idx = blockIdx.x * 256 + threadIdx.x;   // 49152 total
  int d = idx / NN, col = idx - d * NN;
  Wt[col * DP + d] = (__bf16)Wqkv[idx];
}

// Prep: WgT[h][d] = Wg[d][h]; WoT[d][e] = Wo[e][d]  (both 128x128)
__global__ __launch_bounds__(256) void wgo_kernel(
    const float* __restrict__ Wg, const float* __restrict__ Wo,
    __bf16* __restrict__ WgT, __bf16* __restrict__ WoT)
{
  int idx = blockIdx.x * 256 + threadIdx.x;   // 16384 total
  int r = idx >> 7, c = idx & 127;
  WgT[idx] = (__bf16)Wg[c * 128 + r];
  WoT[idx] = (__bf16)Wo[c * 128 + r];
}

// Kernel A: LayerNorm + triangle bias. 32-lane group per position, float4 lanes.
__global__ __launch_bounds__(256) void ln_bias_kernel(
    const float* __restrict__ Zr, const float* __restrict__ lnw,
    const float* __restrict__ lnb, const float* __restrict__ Wb,
    bf16* __restrict__ Zn, float* __restrict__ bias)
{
  int t = threadIdx.x;
  int grp = t >> 5, lane32 = t & 31;
  int pos = blockIdx.x * 8 + grp;
  size_t base = (size_t)pos * DP;
  const float4 x = *(const float4*)(Zr + base + lane32 * 4);
  float s  = x.x + x.y + x.z + x.w;
  float s2 = x.x*x.x + x.y*x.y + x.z*x.z + x.w*x.w;
  #pragma unroll
  for (int m = 1; m < 32; m <<= 1){ s += __shfl_xor(s, m); s2 += __shfl_xor(s2, m); }
  float mean = s * (1.0f / DP);
  float var  = s2 * (1.0f / DP) - mean * mean;
  float rstd = rsqrtf(var + 1e-5f);
  const float4 w4 = *(const float4*)(lnw + lane32 * 4);
  const float4 b4 = *(const float4*)(lnb + lane32 * 4);
  float z0 = (x.x - mean) * rstd * w4.x + b4.x;
  float z1 = (x.y - mean) * rstd * w4.y + b4.y;
  float z2 = (x.z - mean) * rstd * w4.z + b4.z;
  float z3 = (x.w - mean) * rstd * w4.w + b4.w;
  bf16x4 zb = { (__bf16)z0, (__bf16)z1, (__bf16)z2, (__bf16)z3 };
  *(bf16x4*)((__bf16*)Zn + base + lane32 * 4) = zb;
  // bias partials: p[h] = sum_j z_j * Wb[(lane32*4+j)][h]
  const float4 wb0 = *(const float4*)(Wb + (lane32 * 4 + 0) * NHEAD);
  const float4 wb1 = *(const float4*)(Wb + (lane32 * 4 + 1) * NHEAD);
  const float4 wb2 = *(const float4*)(Wb + (lane32 * 4 + 2) * NHEAD);
  const float4 wb3 = *(const float4*)(Wb + (lane32 * 4 + 3) * NHEAD);
  float p0 = z0*wb0.x + z1*wb1.x + z2*wb2.x + z3*wb3.x;
  float p1 = z0*wb0.y + z1*wb1.y + z2*wb2.y + z3*wb3.y;
  float p2 = z0*wb0.z + z1*wb1.z + z2*wb2.z + z3*wb3.z;
  float p3 = z0*wb0.w + z1*wb1.w + z2*wb2.w + z3*wb3.w;
  #pragma unroll
  for (int m = 1; m < 32; m <<= 1){
    p0 += __shfl_xor(p0, m); p1 += __shfl_xor(p1, m);
    p2 += __shfl_xor(p2, m); p3 += __shfl_xor(p3, m);
  }
  if (lane32 == 0){
    bias[0 * NN * NN + pos] = p0;
    bias[1 * NN * NN + pos] = p1;
    bias[2 * NN * NN + pos] = p2;
    bias[3 * NN * NN + pos] = p3;
  }
}

// Kernel B: per (i, head): MFMA qkv projection + MFMA flash attention.
// In-register P + online softmax (R5 body), __launch_bounds__(256, 1):
//  - (256,2) capped the allocator at ~128 arch VGPRs; the bias+mask pass's
//    in-flight float4 loads blew through it -> scratch spill (WRITE 227 MB).
//    LDS (75.3 KB) is the real occupancy limiter (2 blocks/CU); VGPRs only
//    need <=256, which the (256,1) allocation (~180, R0-measured) satisfies.
//  - QK^T computed SWAPPED (mfma(kf, qf)) so each lane's S row is q = m16.
//  - K-tile rows loaded PERMUTED: A-row m sources K-row 8*(m>>2)+(m&3)+4*tb,
//    so lane (m16,quad) holds P[q=m16][k=32*kc+8*quad+j] — exactly the PV
//    A-fragment, built per-lane (no LDS round-trip, no cross-lane ops).
//  - online softmax over two 192-col halves keeps sacc at 12 regsx4.
//  - oacc rows are q=quad*4+reg while the lane's softmax row is q=m16:
//    rescale/normalize factors are fetched with 4 __shfl's (quad-uniform).
// LDS = qs 24K + ks 24K + vs 24K + maskb 1.5K = 75.3 KB -> 2 blocks/CU.
__global__ __launch_bounds__(256, 1) void attn_kernel(
    const __bf16* __restrict__ Zn, const __bf16* __restrict__ Wt,
    const float* __restrict__ Zm, const float* __restrict__ bias,
    __bf16* __restrict__ wa)
{
  __shared__ __align__(128) __bf16 qs[NN * 32];   // q: [row][c] swizzled
  __shared__ __align__(128) __bf16 ks[NN * 32];   // k: [row][c] swizzled
  __shared__ __align__(128) __bf16 vs[CH * NN];   // v^T: [c][row] swizzled
  __shared__ __align__(16) float maskb[NN];

  int i = blockIdx.x >> 2;
  int h = blockIdx.x & 3;
  int t = threadIdx.x;
  int wv = t >> 6;
  int lane = t & 63;
  int m16 = lane & 15;       // low-16 lane id
  int quad = lane >> 4;      // 0..3

  for (int k = t; k < NN; k += 256)
    maskb[k] = (Zm[(size_t)i * NN + k] - 1.0f) * 1e9f;

  const float qscale = 0.17677669529663687f; // 1/sqrt(32)

  // ---- Phase 1: qkv projection via MFMA (identical to R0, swizzled stores) ----
  for (int mt = wv * 6; mt < wv * 6 + 6; mt++){
    bf16x8 afr[4];
    const __bf16* arow = Zn + (size_t)(i * NN + mt * 16 + m16) * DP + quad * 8;
    #pragma unroll
    for (int kc = 0; kc < 4; kc++) afr[kc] = *(const bf16x8*)(arow + kc * 32);
    #pragma unroll
    for (int nt = 0; nt < 6; nt++){
      int mat = nt >> 1;
      int colbase = mat * HCC + h * CH + (nt & 1) * 16;
      const __bf16* brow = Wt + (size_t)(colbase + m16) * DP + quad * 8;
      floatx4 acc = {0.f, 0.f, 0.f, 0.f};
      #pragma unroll
      for (int kc = 0; kc < 4; kc++){
        bf16x8 bfr = *(const bf16x8*)(brow + kc * 32);
        acc = __builtin_amdgcn_mfma_f32_16x16x32_bf16(afr[kc], bfr, acc, 0, 0, 0);
      }
      int ccol = (nt & 1) * 16 + m16;   // 0..31 within head
      #pragma unroll
      for (int reg = 0; reg < 4; reg++){
        int row = mt * 16 + quad * 4 + reg;
        float v = acc[reg];
        if (mat == 0)      qs[(row * 32 + ccol) ^ ((row & 7) << 3)] = (__bf16)(v * qscale);
        else if (mat == 1) ks[(row * 32 + ccol) ^ ((row & 7) << 3)] = (__bf16)v;
        else               vs[(ccol * NN + row) ^ ((ccol & 7) << 3)] = (__bf16)v;
      }
    }
  }
  __syncthreads();

  // ---- Phase 2: attention, per-wave 16-row strips, online softmax ----
  const float* brow_base = bias + (size_t)h * NN * NN;

  for (int s = 0; s < 6; s++){
    int strip = wv * 6 + s;
    int qrow = strip * 16 + m16;
    bf16x8 qf = *(const bf16x8*)(qs + ((qrow * 32 + quad * 8) ^ ((qrow & 7) << 3)));

    float m_run = -1e30f;
    float sm = 0.f;
    floatx4 oacc[2] = {{0.f,0.f,0.f,0.f},{0.f,0.f,0.f,0.f}};

    #pragma unroll
    for (int half = 0; half < 2; half++){
      // QK^T (swapped, permuted K rows): sacc[2*kc2+tb][reg] holds
      // S[q=m16][k = 32*(half*6+kc2) + 8*quad + 4*tb + reg]
      floatx4 sacc[12];
      __builtin_amdgcn_s_setprio(1);
      #pragma unroll
      for (int kc2 = 0; kc2 < 6; kc2++){
        int kc = half * 6 + kc2;
        #pragma unroll
        for (int tb = 0; tb < 2; tb++){
          int krow = kc * 32 + ((m16 & 12) << 1) + tb * 4 + (m16 & 3);
          bf16x8 kf = *(const bf16x8*)(ks + ((krow * 32 + quad * 8) ^ ((krow & 7) << 3)));
          floatx4 z = {0.f, 0.f, 0.f, 0.f};
          sacc[kc2 * 2 + tb] = __builtin_amdgcn_mfma_f32_16x16x32_bf16(kf, qf, z, 0, 0, 0);
        }
      }
      __builtin_amdgcn_s_setprio(0);

      // bias + mask (float4 per reg-group) + local max
      float mx = -1e30f;
      #pragma unroll
      for (int kc2 = 0; kc2 < 6; kc2++){
        int kc = half * 6 + kc2;
        #pragma unroll
        for (int tb = 0; tb < 2; tb++){
          int k0 = kc * 32 + quad * 8 + tb * 4;
          const float4 bb = *(const float4*)(brow_base + (size_t)qrow * NN + k0);
          const float4 mm = *(const float4*)(maskb + k0);
          floatx4 v = sacc[kc2 * 2 + tb];
          v[0] += bb.x + mm.x;
          v[1] += bb.y + mm.y;
          v[2] += bb.z + mm.z;
          v[3] += bb.w + mm.w;
          sacc[kc2 * 2 + tb] = v;
          mx = fmaxf(mx, fmaxf(fmaxf(v[0], v[1]), fmaxf(v[2], v[3])));
        }
      }
      mx = fmaxf(mx, __shfl_xor(mx, 16));
      mx = fmaxf(mx, __shfl_xor(mx, 32));

      float m_new = fmaxf(m_run, mx);
      float scale = __expf(m_run - m_new);   // half 0: exp(-inf) = 0, oacc is 0
      m_run = m_new;
      sm *= scale;
      // redistribute scale to this lane's oacc rows (q = quad*4+reg);
      // scale is quad-uniform, so source lanes 0..15 cover all rows.
      float sc0 = __shfl(scale, quad * 4 + 0);
      float sc1 = __shfl(scale, quad * 4 + 1);
      float sc2 = __shfl(scale, quad * 4 + 2);
      float sc3 = __shfl(scale, quad * 4 + 3);
      #pragma unroll
      for (int ct = 0; ct < 2; ct++){
        oacc[ct][0] *= sc0; oacc[ct][1] *= sc1;
        oacc[ct][2] *= sc2; oacc[ct][3] *= sc3;
      }

      // exp + row-sum + PV (sacc dies here, inside the half)
      #pragma unroll
      for (int kc2 = 0; kc2 < 6; kc2++){
        int kc = half * 6 + kc2;
        floatx4 p0 = sacc[kc2 * 2];
        floatx4 p1 = sacc[kc2 * 2 + 1];
        bf16x8 pa;
        #pragma unroll
        for (int r = 0; r < 4; r++){
          float e0 = __expf(p0[r] - m_run);
          float e1 = __expf(p1[r] - m_run);
          sm += e0 + e1;
          pa[r] = (__bf16)e0;
          pa[r + 4] = (__bf16)e1;
        }
        #pragma unroll
        for (int ct = 0; ct < 2; ct++){
          int c = ct * 16 + m16;
          bf16x8 vb = *(const bf16x8*)(vs + ((c * NN + kc * 32 + quad * 8) ^ ((c & 7) << 3)));
          oacc[ct] = __builtin_amdgcn_mfma_f32_16x16x32_bf16(pa, vb, oacc[ct], 0, 0, 0);
        }
      }
    }

    sm += __shfl_xor(sm, 16);
    sm += __shfl_xor(sm, 32);
    float inv = 1.0f / sm;
    float iv0 = __shfl(inv, quad * 4 + 0);
    float iv1 = __shfl(inv, quad * 4 + 1);
    float iv2 = __shfl(inv, quad * 4 + 2);
    float iv3 = __shfl(inv, quad * 4 + 3);
    float iv[4] = {iv0, iv1, iv2, iv3};
    #pragma unroll
    for (int ct = 0; ct < 2; ct++){
      #pragma unroll
      for (int reg = 0; reg < 4; reg++){
        int row = strip * 16 + quad * 4 + reg;
        wa[(size_t)(i * NN + row) * HCC + h * CH + ct * 16 + m16] =
            (__bf16)(oacc[ct][reg] * iv[reg]);
      }
    }
  }
}

// Kernel C (MFMA): gate = sigmoid(Zn@Wg + gb); out = (gate*wa)@Wo + Zr + ob
// (Proven R0 version.)
__global__ __launch_bounds__(256, 1) void out_kernel(
    const float* __restrict__ Zr, const __bf16* __restrict__ Zn,
    const __bf16* __restrict__ wa, const __bf16* __restrict__ WgT,
    const float* __restrict__ gb, const __bf16* __restrict__ WoT,
    const float* __restrict__ ob, float* __restrict__ out)
{
  __shared__ __align__(16) __bf16 wgs[128 * WSTRIDE];       // [h][d]
  __shared__ __align__(16) __bf16 wos[128 * WSTRIDE];       // [d][e]
  __shared__ __align__(16) __bf16 gsh[4][16 * WSTRIDE];     // per-wave G strip
  __shared__ float gbs[HCC], obs[DP];

  int t = threadIdx.x;
  int wv = t >> 6, lane = t & 63;
  int m16 = lane & 15, quad = lane >> 4;

  for (int idx = t * 8; idx < 128 * 128; idx += 256 * 8){
    int r = idx >> 7, c = idx & 127;
    *(bf16x8*)(wgs + r * WSTRIDE + c) = *(const bf16x8*)(WgT + idx);
    *(bf16x8*)(wos + r * WSTRIDE + c) = *(const bf16x8*)(WoT + idx);
  }
  if (t < 128){ gbs[t] = gb[t]; obs[t] = ob[t]; }
  __syncthreads();

  int mbase = blockIdx.x * 128;
  __bf16* gstrip = gsh[wv];

  for (int sp = 0; sp < 2; sp++){
    int row0 = mbase + (sp * 4 + wv) * 16;
    // gate GEMM: A from Zn rows, B from wgs
    bf16x8 afr[4];
    const __bf16* arow = Zn + (size_t)(row0 + m16) * DP + quad * 8;
    #pragma unroll
    for (int kc = 0; kc < 4; kc++) afr[kc] = *(const bf16x8*)(arow + kc * 32);
    #pragma unroll
    for (int nt = 0; nt < 8; nt++){
      floatx4 acc = {0.f, 0.f, 0.f, 0.f};
      #pragma unroll
      for (int kc = 0; kc < 4; kc++){
        bf16x8 bfr = *(const bf16x8*)(wgs + (nt * 16 + m16) * WSTRIDE + kc * 32 + quad * 8);
        acc = __builtin_amdgcn_mfma_f32_16x16x32_bf16(afr[kc], bfr, acc, 0, 0, 0);
      }
      int col = nt * 16 + m16;
      #pragma unroll
      for (int reg = 0; reg < 4; reg++){
        int row = row0 + quad * 4 + reg;
        float g = 1.0f / (1.0f + __expf(-(acc[reg] + gbs[col])));
        float w = b2f(wa[(size_t)row * HCC + col]);
        gstrip[(quad * 4 + reg) * WSTRIDE + col] = f2b(g * w);
      }
    }
    // out GEMM: A from gstrip (same wave — lockstep, compiler inserts lgkmcnt waits)
    bf16x8 gfr[4];
    #pragma unroll
    for (int kc = 0; kc < 4; kc++)
      gfr[kc] = *(const bf16x8*)(gstrip + m16 * WSTRIDE + kc * 32 + quad * 8);
    #pragma unroll
    for (int nt = 0; nt < 8; nt++){
      floatx4 acc = {0.f, 0.f, 0.f, 0.f};
      #pragma unroll
      for (int kc = 0; kc < 4; kc++){
        bf16x8 bfr = *(const bf16x8*)(wos + (nt * 16 + m16) * WSTRIDE + kc * 32 + quad * 8);
        acc = __builtin_amdgcn_mfma_f32_16x16x32_bf16(gfr[kc], bfr, acc, 0, 0, 0);
      }
      int col = nt * 16 + m16;
      #pragma unroll
      for (int reg = 0; reg < 4; reg++){
        int row = row0 + quad * 4 + reg;
        size_t off = (size_t)row * DP + col;
        out[off] = Zr[off] + acc[reg] + obs[col];
      }
    }
  }
}

extern "C" void kernel_launch(void* const* d_in, const int* in_sizes, int n_in,
                              void* d_out, int out_size, void* d_ws, size_t ws_size,
                              hipStream_t stream)
{
  const float* Zr   = (const float*)d_in[0];
  const float* Zm   = (const float*)d_in[1];
  const float* lnw  = (const float*)d_in[2];
  const float* lnb  = (const float*)d_in[3];
  const float* Wb   = (const float*)d_in[4];
  const float* Wqkv = (const float*)d_in[5];
  const float* Wg   = (const float*)d_in[6];
  const float* gb   = (const float*)d_in[7];
  const float* Wo   = (const float*)d_in[8];
  const float* ob   = (const float*)d_in[9];
  float* out = (float*)d_out;

  char* ws = (char*)d_ws;
  // ws: Zn bf16 | bias fp32 | wa bf16 | Wt bf16 | WgT bf16 | WoT bf16
  size_t off = 0;
  bf16*   Zn   = (bf16*)(ws + off);           off += (size_t)NN * NN * DP * 2;
  float*  bias = (float*)(ws + off);          off += (size_t)NHEAD * NN * NN * 4;
  bf16*   wa   = (bf16*)(ws + off);           off += (size_t)NN * NN * HCC * 2;
  __bf16* Wt   = (__bf16*)(ws + off);         off += (size_t)3 * HCC * DP * 2;
  __bf16* WgT  = (__bf16*)(ws + off);         off += (size_t)DP * HCC * 2;
  __bf16* WoT  = (__bf16*)(ws + off);         off += (size_t)HCC * DP * 2;

  wt_kernel<<<(3 * HCC * DP) / 256, 256, 0, stream>>>(Wqkv, Wt);
  wgo_kernel<<<(DP * HCC) / 256, 256, 0, stream>>>(Wg, Wo, WgT, WoT);
  ln_bias_kernel<<<NN * NN / 8, 256, 0, stream>>>(Zr, lnw, lnb, Wb, Zn, bias);
  attn_kernel<<<NN * NHEAD, 256, 0, stream>>>((const __bf16*)Zn, Wt, Zm, bias, (__bf16*)wa);
  out_kernel<<<NN * NN / 128, 256, 0, stream>>>(Zr, (const __bf16*)Zn, (const __bf16*)wa,
                                                WgT, gb, WoT, ob, out);
}